// Round 6
// baseline (195.922 us; speedup 1.0000x reference)
//
#include <hip/hip_runtime.h>
#include <hip/hip_bf16.h>

#define ROWS   8192
#define DIM    512
#define NCODES 8192
#define MARGIN 0.75f

using bf16x8 = __attribute__((ext_vector_type(8))) short;
using f32x4  = __attribute__((ext_vector_type(4))) float;
typedef unsigned short ushort_t;

__device__ __forceinline__ void gload_lds16(const void* g, void* l) {
    __builtin_amdgcn_global_load_lds((const __attribute__((address_space(1))) void*)g,
                                     (__attribute__((address_space(3))) void*)l,
                                     16, 0, 0);
}

__device__ __forceinline__ unsigned short f2bf_rne(float f) {
    unsigned int u = __float_as_uint(f);
    u = (u + 0x7FFFu + ((u >> 16) & 1u)) >> 16;
    return (unsigned short)u;
}

// ---------- Kernel 1: LN stats + bf16(h) rows, and bf16(embd) rows ----------
__global__ __launch_bounds__(256) void prep_kernel(
    const float* __restrict__ x, const float* __restrict__ lw,
    const float* __restrict__ lb, const float* __restrict__ embd,
    float2* __restrict__ stats, ushort_t* __restrict__ Hb,
    ushort_t* __restrict__ Eb)
{
    const int w    = threadIdx.x >> 6;
    const int lane = threadIdx.x & 63;
    const int b    = blockIdx.x;

    if (b < 2048) {
        const int row = b * 4 + w;
        const float* xr = x + (size_t)row * DIM + lane * 8;
        float4 v0 = *(const float4*)(xr);
        float4 v1 = *(const float4*)(xr + 4);
        float s = (v0.x + v0.y) + (v0.z + v0.w) + (v1.x + v1.y) + (v1.z + v1.w);
        float q = v0.x*v0.x + v0.y*v0.y + v0.z*v0.z + v0.w*v0.w
                + v1.x*v1.x + v1.y*v1.y + v1.z*v1.z + v1.w*v1.w;
        #pragma unroll
        for (int off = 1; off < 64; off <<= 1) {
            s += __shfl_xor(s, off);
            q += __shfl_xor(q, off);
        }
        float mu   = s * (1.0f / DIM);
        float var  = q * (1.0f / DIM) - mu * mu;
        float rstd = rsqrtf(var + 1e-5f);
        if (lane == 0) stats[row] = make_float2(mu, rstd);

        float4 w0 = *(const float4*)(lw + lane * 8);
        float4 w1 = *(const float4*)(lw + lane * 8 + 4);
        float4 b0 = *(const float4*)(lb + lane * 8);
        float4 b1 = *(const float4*)(lb + lane * 8 + 4);
        float hv[8] = {
            (v0.x - mu) * rstd * w0.x + b0.x, (v0.y - mu) * rstd * w0.y + b0.y,
            (v0.z - mu) * rstd * w0.z + b0.z, (v0.w - mu) * rstd * w0.w + b0.w,
            (v1.x - mu) * rstd * w1.x + b1.x, (v1.y - mu) * rstd * w1.y + b1.y,
            (v1.z - mu) * rstd * w1.z + b1.z, (v1.w - mu) * rstd * w1.w + b1.w };
        union { unsigned short u[8]; uint4 v; } p;
        #pragma unroll
        for (int j = 0; j < 8; ++j) p.u[j] = f2bf_rne(hv[j]);
        *(uint4*)(Hb + (size_t)row * DIM + lane * 8) = p.v;
    } else {
        const int row = (b - 2048) * 4 + w;
        const float* er = embd + (size_t)row * DIM + lane * 8;
        float4 v0 = *(const float4*)(er);
        float4 v1 = *(const float4*)(er + 4);
        float ev[8] = { v0.x, v0.y, v0.z, v0.w, v1.x, v1.y, v1.z, v1.w };
        union { unsigned short u[8]; uint4 v; } p;
        #pragma unroll
        for (int j = 0; j < 8; ++j) p.u[j] = f2bf_rne(ev[j]);
        *(uint4*)(Eb + (size_t)row * DIM + lane * 8) = p.v;
    }
}

// ---------- Kernel 2: A-panel-resident GEMM + per-lane top-2 ----------
// 256 blocks (1/CU), 256 threads (4 waves 2x2). Block = 128 rows x 2048 cols.
// A-panel 128x512 bf16 = 128 KB LDS (XOR-swizzled rows, pre-swizzled source);
// B streamed as 128x32 tiles through 3-slot ring (24 KB), vmcnt(2) counted,
// ONE barrier per iteration. 256 iterations (16 nt x 16 kt).
// Argmax: per-lane running top-2 over the lane's 64-col class; 256 cand/row.
__global__ __launch_bounds__(256, 1) void gemm_argmax_kernel(
    const ushort_t* __restrict__ Hb, const ushort_t* __restrict__ Eb,
    float* __restrict__ pval, int* __restrict__ pidx)
{
    __shared__ __align__(16) ushort_t Alds[128 * DIM];      // 128 KB
    __shared__ __align__(16) ushort_t Blds[3][128 * 32];    // 24 KB

    const int tid  = threadIdx.x;
    const int w    = tid >> 6;
    const int lane = tid & 63;
    const int r_   = lane & 15;
    const int g    = lane >> 4;
    const int wr   = w >> 1;          // row half (0,1) -> 64 rows
    const int wc   = w & 1;           // col half (0,1) -> 64 cols per nt

    // XCD map: xcd = bid&7 -> col-group (xcd&3); 2 XCDs share a 2MB B-stream.
    const int bid  = blockIdx.x;
    const int xcd  = bid & 7;
    const int s_   = bid >> 3;                 // 0..31
    const int colg = xcd & 3;
    const int rowp = ((xcd >> 2) << 5) | s_;   // 0..63
    const int r0   = rowp * 128;
    const int cg0  = colg * 2048;

    // ---- A-panel staging: 32 gloads/wave, one 1KB row each, source swizzled
    //      LDS[ja*512 + u] = H[r0+ja][u ^ ((ja&7)<<3)]
    #pragma unroll
    for (int j = 0; j < 32; ++j) {
        const int ja = w * 32 + j;
        gload_lds16(Hb + (size_t)(r0 + ja) * DIM + ((lane ^ (j & 7)) * 8),
                    &Alds[ja * 512]);
    }

    // ---- B staging geometry: tile 128 cols x 32 k = 8 gloads; wave does 2.
    const size_t eb_off0 = (size_t)(cg0 + (w * 2 + 0) * 16 + (lane >> 2)) * DIM + (lane & 3) * 8;
    const size_t eb_off1 = (size_t)(cg0 + (w * 2 + 1) * 16 + (lane >> 2)) * DIM + (lane & 3) * 8;
    const ushort_t* eb0 = Eb + eb_off0;
    const ushort_t* eb1 = Eb + eb_off1;

#define STAGE_B(SL, NT2, KT2) do {                                    \
        const size_t off_ = (size_t)(NT2) * (128 * DIM) + (KT2) * 32; \
        gload_lds16(eb0 + off_, &Blds[SL][(w * 2 + 0) * 512]);        \
        gload_lds16(eb1 + off_, &Blds[SL][(w * 2 + 1) * 512]);        \
    } while (0)
#define VMW(N) asm volatile("s_waitcnt vmcnt(" #N ")" ::: "memory")
#define BAR() do { asm volatile("" ::: "memory");                     \
                   __builtin_amdgcn_s_barrier();                      \
                   asm volatile("" ::: "memory"); } while (0)
#define MF(M, N, AV, BV) \
        acc[M][N] = __builtin_amdgcn_mfma_f32_16x16x32_bf16(AV, BV, acc[M][N], 0, 0, 0)

    // prologue: A-panel (32/wave), then B(0)->slot0, B(1)->slot1.
    STAGE_B(0, 0, 0);
    STAGE_B(1, 0, 1);
    // loop iter 0's VMW(2) drains A + B(0), leaves B(1) in flight.

    // per-lane running top-2 state over this lane's 64-col class
    float v1a[4][4], v2a[4][4];
    int   i1a[4][4], i2a[4][4];
    #pragma unroll
    for (int m = 0; m < 4; ++m)
        #pragma unroll
        for (int reg = 0; reg < 4; ++reg) {
            v1a[m][reg] = -3.4e38f; v2a[m][reg] = -3.4e38f;
            i1a[m][reg] = 0x7fffffff; i2a[m][reg] = 0x7fffffff;
        }

    const int fldA = (r_ & 7) << 3;                 // ushort XOR field
    const int arow0 = (wr * 64 + r_) * 512;         // + m*16*512
    const int bcol0 = (wc * 64 + r_) * 32 + g * 8;  // + n*16*32

    int snt = 0;                                    // nt % 3
    for (int nt = 0; nt < 16; ++nt) {
        f32x4 acc[4][4];
        #pragma unroll
        for (int m = 0; m < 4; ++m)
            #pragma unroll
            for (int n = 0; n < 4; ++n) acc[m][n] = (f32x4){0.f, 0.f, 0.f, 0.f};

        #pragma unroll
        for (int kt = 0; kt < 16; ++kt) {
            // vmcnt: all but newest-2 landed => B(it) landed. Tail drains.
            if (kt == 15) { if (nt == 15) { VMW(0); } else { VMW(2); } }
            else          { VMW(2); }
            BAR();

            // stage B(it+2) AFTER the barrier (WAR-safe: the overwritten
            // slot's reads completed before this barrier via MFMA lgkm deps)
            int sl2 = snt + ((kt + 2) % 3); if (sl2 >= 3) sl2 -= 3;
            if (kt <= 13)            STAGE_B(sl2, nt, kt + 2);
            else if (nt < 15) {
                if (kt == 14)        STAGE_B(sl2, nt + 1, 0);
                else                 STAGE_B(sl2, nt + 1, 1);
            }

            int sl = snt + (kt % 3); if (sl >= 3) sl -= 3;
            const int ak = (kt * 32 + g * 8) ^ fldA;
            bf16x8 a0 = *(const bf16x8*)&Alds[arow0 + 0 * 8192 + ak];
            bf16x8 a1 = *(const bf16x8*)&Alds[arow0 + 1 * 8192 + ak];
            bf16x8 a2 = *(const bf16x8*)&Alds[arow0 + 2 * 8192 + ak];
            bf16x8 a3 = *(const bf16x8*)&Alds[arow0 + 3 * 8192 + ak];
            bf16x8 b0 = *(const bf16x8*)&Blds[sl][bcol0 + 0 * 512];
            bf16x8 b1 = *(const bf16x8*)&Blds[sl][bcol0 + 1 * 512];
            bf16x8 b2 = *(const bf16x8*)&Blds[sl][bcol0 + 2 * 512];
            bf16x8 b3 = *(const bf16x8*)&Blds[sl][bcol0 + 3 * 512];

            __builtin_amdgcn_s_setprio(1);
            MF(0, 0, a0, b0); MF(0, 1, a0, b1); MF(0, 2, a0, b2); MF(0, 3, a0, b3);
            MF(1, 0, a1, b0); MF(1, 1, a1, b1); MF(1, 2, a1, b2); MF(1, 3, a1, b3);
            MF(2, 0, a2, b0); MF(2, 1, a2, b1); MF(2, 2, a2, b2); MF(2, 3, a2, b3);
            MF(3, 0, a3, b0); MF(3, 1, a3, b1); MF(3, 2, a3, b2); MF(3, 3, a3, b3);
            __builtin_amdgcn_s_setprio(0);
        }

        // ---- fold this nt's acc into per-lane running top-2 (regs only) ----
        #pragma unroll
        for (int m = 0; m < 4; ++m)
            #pragma unroll
            for (int reg = 0; reg < 4; ++reg)
                #pragma unroll
                for (int n = 0; n < 4; ++n) {
                    const float val = acc[m][n][reg];
                    const int   col = cg0 + nt * 128 + wc * 64 + n * 16 + r_;
                    if (val > v1a[m][reg]) {
                        v2a[m][reg] = v1a[m][reg]; i2a[m][reg] = i1a[m][reg];
                        v1a[m][reg] = val;         i1a[m][reg] = col;
                    } else if (val > v2a[m][reg]) {
                        v2a[m][reg] = val; i2a[m][reg] = col;
                    }
                }

        snt = (snt == 2) ? 0 : snt + 1;
    }

#undef MF
#undef BAR
#undef VMW
#undef STAGE_B

    // ---- stores: each lane owns chunk (colg*64 + wc*32 + r_*2) of 256/row ----
    const int cb2 = colg * 64 + wc * 32 + r_ * 2;
    #pragma unroll
    for (int m = 0; m < 4; ++m)
        #pragma unroll
        for (int reg = 0; reg < 4; ++reg) {
            const int row = r0 + wr * 64 + m * 16 + g * 4 + reg;
            const size_t base = (size_t)row * 256 + cb2;
            pval[base]     = v1a[m][reg];
            pval[base + 1] = v2a[m][reg];
            pidx[base]     = i1a[m][reg];
            pidx[base + 1] = i2a[m][reg];
        }
}

// ---------- Kernel 3: exact fp32 re-check of candidates + gather ----------
__global__ __launch_bounds__(256) void finalize_kernel(
    const float* __restrict__ x, const float* __restrict__ lw,
    const float* __restrict__ lb, const float* __restrict__ embd,
    const float2* __restrict__ stats,
    const float* __restrict__ pval, const int* __restrict__ pidx,
    float* __restrict__ outq, float* __restrict__ outi)
{
    const int w    = threadIdx.x >> 6;
    const int lane = threadIdx.x & 63;
    const int row  = blockIdx.x * 4 + w;

    const float4 cv = *(const float4*)&pval[(size_t)row * 256 + lane * 4];
    const int4   ci = *(const int4*)  &pidx[(size_t)row * 256 + lane * 4];
    float vv[4] = { cv.x, cv.y, cv.z, cv.w };
    int   ii[4] = { ci.x, ci.y, ci.z, ci.w };

    float M = fmaxf(fmaxf(vv[0], vv[1]), fmaxf(vv[2], vv[3]));
    #pragma unroll
    for (int off = 1; off < 64; off <<= 1) M = fmaxf(M, __shfl_xor(M, off));
    const float T = M - MARGIN;

    const float2 st = stats[row];
    const float mu = st.x, rstd = st.y;
    const float* xr = x + (size_t)row * DIM + lane * 8;
    float4 x0 = *(const float4*)(xr);
    float4 x1 = *(const float4*)(xr + 4);
    float4 w0 = *(const float4*)(lw + lane * 8);
    float4 w1 = *(const float4*)(lw + lane * 8 + 4);
    float4 b0 = *(const float4*)(lb + lane * 8);
    float4 b1 = *(const float4*)(lb + lane * 8 + 4);
    float h[8] = {
        (x0.x - mu) * rstd * w0.x + b0.x, (x0.y - mu) * rstd * w0.y + b0.y,
        (x0.z - mu) * rstd * w0.z + b0.z, (x0.w - mu) * rstd * w0.w + b0.w,
        (x1.x - mu) * rstd * w1.x + b1.x, (x1.y - mu) * rstd * w1.y + b1.y,
        (x1.z - mu) * rstd * w1.z + b1.z, (x1.w - mu) * rstd * w1.w + b1.w };

    float bestv = -3.4e38f; int besti = 0x7fffffff;
    #pragma unroll
    for (int s = 0; s < 4; ++s) {
        unsigned long long msk = __ballot(vv[s] >= T);
        while (msk) {
            const int L = __ffsll(msk) - 1;
            msk &= msk - 1;
            const int cand = __shfl(ii[s], L);
            const float* er = embd + (size_t)cand * DIM + lane * 8;
            float4 e0 = *(const float4*)er;
            float4 e1 = *(const float4*)(er + 4);
            float d = h[0]*e0.x + h[1]*e0.y + h[2]*e0.z + h[3]*e0.w
                    + h[4]*e1.x + h[5]*e1.y + h[6]*e1.z + h[7]*e1.w;
            #pragma unroll
            for (int off = 1; off < 64; off <<= 1) d += __shfl_xor(d, off);
            if (d > bestv || (d == bestv && cand < besti)) { bestv = d; besti = cand; }
        }
    }

    const float* er = embd + (size_t)besti * DIM + lane * 8;
    float4 q0 = *(const float4*)er;
    float4 q1 = *(const float4*)(er + 4);
    float* qr = outq + (size_t)row * DIM + lane * 8;
    *(float4*)(qr)     = q0;
    *(float4*)(qr + 4) = q1;
    if (lane == 0) outi[row] = (float)besti;
}

extern "C" void kernel_launch(void* const* d_in, const int* in_sizes, int n_in,
                              void* d_out, int out_size, void* d_ws, size_t ws_size,
                              hipStream_t stream) {
    const float* x    = (const float*)d_in[0];
    const float* lnw  = (const float*)d_in[1];
    const float* lnb  = (const float*)d_in[2];
    const float* embd = (const float*)d_in[3];

    float* outq = (float*)d_out;
    float* outi = outq + (size_t)ROWS * DIM;

    char* ws = (char*)d_ws;
    float2*   stats = (float2*)ws;                                   // 64 KiB
    ushort_t* Hb    = (ushort_t*)(ws + (1 << 16));                   // 8 MiB
    ushort_t* Eb    = (ushort_t*)(ws + (1 << 16) + (8 << 20));       // 8 MiB
    float*    pval  = (float*)(ws + (1 << 16) + (16 << 20));         // 8 MiB
    int*      pidx  = (int*)  (ws + (1 << 16) + (24 << 20));         // 8 MiB

    prep_kernel<<<4096, 256, 0, stream>>>(x, lnw, lnb, embd, stats, Hb, Eb);

    gemm_argmax_kernel<<<256, 256, 0, stream>>>(Hb, Eb, pval, pidx);

    finalize_kernel<<<ROWS / 4, 256, 0, stream>>>(x, lnw, lnb, embd, stats,
                                                  pval, pidx, outq, outi);
}

// Round 7
// 164.683 us; speedup vs baseline: 1.1897x; 1.1897x over previous
//
#include <hip/hip_runtime.h>
#include <hip/hip_bf16.h>

#define ROWS   8192
#define DIM    512
#define NCODES 8192
#define BM     256
#define BN     128
#define BK     32
#define NT     (DIM / BK)             // 16 K-tiles
#define MARGIN 0.75f

using bf16x8 = __attribute__((ext_vector_type(8))) short;
using f32x4  = __attribute__((ext_vector_type(4))) float;
typedef unsigned short ushort_t;

__device__ __forceinline__ void gload_lds16(const void* g, void* l) {
    __builtin_amdgcn_global_load_lds((const __attribute__((address_space(1))) void*)g,
                                     (__attribute__((address_space(3))) void*)l,
                                     16, 0, 0);
}

__device__ __forceinline__ unsigned short f2bf_rne(float f) {
    unsigned int u = __float_as_uint(f);
    u = (u + 0x7FFFu + ((u >> 16) & 1u)) >> 16;
    return (unsigned short)u;
}

// ---------- Kernel 1: LN stats + bf16(h) rows, and bf16(embd) rows ----------
__global__ __launch_bounds__(256) void prep_kernel(
    const float* __restrict__ x, const float* __restrict__ lw,
    const float* __restrict__ lb, const float* __restrict__ embd,
    float2* __restrict__ stats, ushort_t* __restrict__ Hb,
    ushort_t* __restrict__ Eb)
{
    const int w    = threadIdx.x >> 6;
    const int lane = threadIdx.x & 63;
    const int b    = blockIdx.x;

    if (b < 2048) {
        const int row = b * 4 + w;
        const float* xr = x + (size_t)row * DIM + lane * 8;
        float4 v0 = *(const float4*)(xr);
        float4 v1 = *(const float4*)(xr + 4);
        float s = (v0.x + v0.y) + (v0.z + v0.w) + (v1.x + v1.y) + (v1.z + v1.w);
        float q = v0.x*v0.x + v0.y*v0.y + v0.z*v0.z + v0.w*v0.w
                + v1.x*v1.x + v1.y*v1.y + v1.z*v1.z + v1.w*v1.w;
        #pragma unroll
        for (int off = 1; off < 64; off <<= 1) {
            s += __shfl_xor(s, off);
            q += __shfl_xor(q, off);
        }
        float mu   = s * (1.0f / DIM);
        float var  = q * (1.0f / DIM) - mu * mu;
        float rstd = rsqrtf(var + 1e-5f);
        if (lane == 0) stats[row] = make_float2(mu, rstd);

        float4 w0 = *(const float4*)(lw + lane * 8);
        float4 w1 = *(const float4*)(lw + lane * 8 + 4);
        float4 b0 = *(const float4*)(lb + lane * 8);
        float4 b1 = *(const float4*)(lb + lane * 8 + 4);
        float hv[8] = {
            (v0.x - mu) * rstd * w0.x + b0.x, (v0.y - mu) * rstd * w0.y + b0.y,
            (v0.z - mu) * rstd * w0.z + b0.z, (v0.w - mu) * rstd * w0.w + b0.w,
            (v1.x - mu) * rstd * w1.x + b1.x, (v1.y - mu) * rstd * w1.y + b1.y,
            (v1.z - mu) * rstd * w1.z + b1.z, (v1.w - mu) * rstd * w1.w + b1.w };
        union { unsigned short u[8]; uint4 v; } p;
        #pragma unroll
        for (int j = 0; j < 8; ++j) p.u[j] = f2bf_rne(hv[j]);
        *(uint4*)(Hb + (size_t)row * DIM + lane * 8) = p.v;
    } else {
        const int row = (b - 2048) * 4 + w;
        const float* er = embd + (size_t)row * DIM + lane * 8;
        float4 v0 = *(const float4*)(er);
        float4 v1 = *(const float4*)(er + 4);
        float ev[8] = { v0.x, v0.y, v0.z, v0.w, v1.x, v1.y, v1.z, v1.w };
        union { unsigned short u[8]; uint4 v; } p;
        #pragma unroll
        for (int j = 0; j < 8; ++j) p.u[j] = f2bf_rne(ev[j]);
        *(uint4*)(Eb + (size_t)row * DIM + lane * 8) = p.v;
    }
}

// ---------- Kernel 2: 256x128 bf16 MFMA GEMM, 2 blocks/CU, dbuf counted ----
// 256 threads = 4 waves (2 row x 2 col); per-wave output 128x64 (acc[8][4]).
// LDS: 2 slots x (A 16KB + B 8KB) = 48 KB -> 2 independent blocks co-resident
// per CU (96 KB LDS, 8 waves at ~240 unified regs). The co-residency provides
// the stall overlap that single-block schedule tuning (R3-R5) could not.
// T2 swizzle byte^=((row>>1)&3)<<4 on BOTH A and B (R4-verified: 0 conflicts).
__global__ __launch_bounds__(256, 2) void gemm_argmax_kernel(
    const ushort_t* __restrict__ Hb, const ushort_t* __restrict__ Eb,
    float* __restrict__ pval, int* __restrict__ pidx)
{
    __shared__ __align__(16) ushort_t As[2][BM * BK];   // 2 x 16 KB
    __shared__ __align__(16) ushort_t Bs[2][BN * BK];   // 2 x 8 KB

    const int tid  = threadIdx.x;
    const int w    = tid >> 6;
    const int lane = tid & 63;
    const int r_   = lane & 15;
    const int g    = lane >> 4;
    const int wr   = w >> 1;          // row half (0,1) -> 128 rows
    const int wc   = w & 1;           // col half (0,1) -> 64 cols

    // T1: XCD map. xcd = bid&7 owns 4 row-panels x all 64 col-tiles, col-major.
    const int bid  = blockIdx.x;
    const int trow = ((bid & 7) << 2) | ((bid >> 3) & 3);   // 0..31
    const int tcol = bid >> 5;                              // 0..63
    const int r0 = trow * BM;
    const int n0 = tcol * BN;

    // ---- staging geometry: per K-tile A=16KB (4 gloads/thread), B=8KB (2).
    // dest byte d = seg*1024 + lane*16 -> drow = seg*16+(lane>>2),
    // dcol=(lane&3)*16; inverse-swizzled SOURCE col byte = dcol ^ ((drow>>1)&3)<<4.
    const int da0 = (w * 4 + 0) * 16 + (lane >> 2);
    const int da1 = (w * 4 + 1) * 16 + (lane >> 2);
    const int da2 = (w * 4 + 2) * 16 + (lane >> 2);
    const int da3 = (w * 4 + 3) * 16 + (lane >> 2);
    const int db0 = (w * 2 + 0) * 16 + (lane >> 2);
    const int db1 = (w * 2 + 1) * 16 + (lane >> 2);
    const int lc  = (lane & 3) * 16;
    const ushort_t* sA0 = Hb + (size_t)(r0 + da0) * DIM + ((lc ^ (((da0 >> 1) & 3) << 4)) >> 1);
    const ushort_t* sA1 = Hb + (size_t)(r0 + da1) * DIM + ((lc ^ (((da1 >> 1) & 3) << 4)) >> 1);
    const ushort_t* sA2 = Hb + (size_t)(r0 + da2) * DIM + ((lc ^ (((da2 >> 1) & 3) << 4)) >> 1);
    const ushort_t* sA3 = Hb + (size_t)(r0 + da3) * DIM + ((lc ^ (((da3 >> 1) & 3) << 4)) >> 1);
    const ushort_t* sB0 = Eb + (size_t)(n0 + db0) * DIM + ((lc ^ (((db0 >> 1) & 3) << 4)) >> 1);
    const ushort_t* sB1 = Eb + (size_t)(n0 + db1) * DIM + ((lc ^ (((db1 >> 1) & 3) << 4)) >> 1);
    const int ua0 = (w * 4 + 0) * 512, ua1 = (w * 4 + 1) * 512;
    const int ua2 = (w * 4 + 2) * 512, ua3 = (w * 4 + 3) * 512;
    const int ub0 = (w * 2 + 0) * 512, ub1 = (w * 2 + 1) * 512;

    // swizzled ds_read bases (byte offsets within a slot)
    const int swz   = ((r_ >> 1) & 3) << 4;
    const int abase = (wr * 128 + r_) * 64 + ((g * 16) ^ swz);   // + m*1024
    const int bbase = (wc * 64  + r_) * 64 + ((g * 16) ^ swz);   // + n*1024

    f32x4 acc[8][4];
    #pragma unroll
    for (int m = 0; m < 8; ++m)
        #pragma unroll
        for (int n = 0; n < 4; ++n) acc[m][n] = (f32x4){0.f, 0.f, 0.f, 0.f};

#define STAGE(T) do {                                               \
        const int _ko = (T) * BK;                                   \
        const int _bf = (T) & 1;                                    \
        gload_lds16(sA0 + _ko, &As[_bf][ua0]);                      \
        gload_lds16(sA1 + _ko, &As[_bf][ua1]);                      \
        gload_lds16(sA2 + _ko, &As[_bf][ua2]);                      \
        gload_lds16(sA3 + _ko, &As[_bf][ua3]);                      \
        gload_lds16(sB0 + _ko, &Bs[_bf][ub0]);                      \
        gload_lds16(sB1 + _ko, &Bs[_bf][ub1]);                      \
    } while (0)
#define MF(M, N, AV, BV) \
        acc[M][N] = __builtin_amdgcn_mfma_f32_16x16x32_bf16(AV, BV, acc[M][N], 0, 0, 0)

    STAGE(0);

    #pragma unroll
    for (int t = 0; t < NT; ++t) {
        if (t + 1 < NT) {
            STAGE(t + 1);
            asm volatile("s_waitcnt vmcnt(6)" ::: "memory");  // tile t landed
        } else {
            asm volatile("s_waitcnt vmcnt(0)" ::: "memory");
        }
        __builtin_amdgcn_s_barrier();

        const char* Ab = (const char*)&As[t & 1][0];
        const char* Bb = (const char*)&Bs[t & 1][0];
        bf16x8 a0 = *(const bf16x8*)(Ab + abase + 0 * 1024);
        bf16x8 a1 = *(const bf16x8*)(Ab + abase + 1 * 1024);
        bf16x8 a2 = *(const bf16x8*)(Ab + abase + 2 * 1024);
        bf16x8 a3 = *(const bf16x8*)(Ab + abase + 3 * 1024);
        bf16x8 a4 = *(const bf16x8*)(Ab + abase + 4 * 1024);
        bf16x8 a5 = *(const bf16x8*)(Ab + abase + 5 * 1024);
        bf16x8 a6 = *(const bf16x8*)(Ab + abase + 6 * 1024);
        bf16x8 a7 = *(const bf16x8*)(Ab + abase + 7 * 1024);
        bf16x8 b0 = *(const bf16x8*)(Bb + bbase + 0 * 1024);
        bf16x8 b1 = *(const bf16x8*)(Bb + bbase + 1 * 1024);
        bf16x8 b2 = *(const bf16x8*)(Bb + bbase + 2 * 1024);
        bf16x8 b3 = *(const bf16x8*)(Bb + bbase + 3 * 1024);

        __builtin_amdgcn_s_setprio(1);
        MF(0, 0, a0, b0); MF(0, 1, a0, b1); MF(0, 2, a0, b2); MF(0, 3, a0, b3);
        MF(1, 0, a1, b0); MF(1, 1, a1, b1); MF(1, 2, a1, b2); MF(1, 3, a1, b3);
        MF(2, 0, a2, b0); MF(2, 1, a2, b1); MF(2, 2, a2, b2); MF(2, 3, a2, b3);
        MF(3, 0, a3, b0); MF(3, 1, a3, b1); MF(3, 2, a3, b2); MF(3, 3, a3, b3);
        MF(4, 0, a4, b0); MF(4, 1, a4, b1); MF(4, 2, a4, b2); MF(4, 3, a4, b3);
        MF(5, 0, a5, b0); MF(5, 1, a5, b1); MF(5, 2, a5, b2); MF(5, 3, a5, b3);
        MF(6, 0, a6, b0); MF(6, 1, a6, b1); MF(6, 2, a6, b2); MF(6, 3, a6, b3);
        MF(7, 0, a7, b0); MF(7, 1, a7, b1); MF(7, 2, a7, b2); MF(7, 3, a7, b3);
        __builtin_amdgcn_s_setprio(0);

        __builtin_amdgcn_s_barrier();   // closing: slot (t&1) readers done
    }

#undef MF
#undef STAGE

    // ---- epilogue: per-row top-2 over this wave's 64-col chunk ----
    const int cb = n0 + wc * 64;
    #pragma unroll
    for (int m = 0; m < 8; ++m) {
        #pragma unroll
        for (int reg = 0; reg < 4; ++reg) {
            float v1 = acc[m][0][reg]; int i1 = cb + r_;
            float v2 = -3.4e38f;       int i2 = 0;
            #pragma unroll
            for (int n = 1; n < 4; ++n) {
                float vv = acc[m][n][reg];
                int   cc = cb + n * 16 + r_;
                if (vv > v1)      { v2 = v1; i2 = i1; v1 = vv; i1 = cc; }
                else if (vv > v2) { v2 = vv; i2 = cc; }
            }
            #pragma unroll
            for (int off = 1; off < 16; off <<= 1) {
                float u1 = __shfl_xor(v1, off);
                int   j1 = __shfl_xor(i1, off);
                float u2 = __shfl_xor(v2, off);
                int   j2 = __shfl_xor(i2, off);
                if (u1 > v1) {
                    if (v1 > u2) { v2 = v1; i2 = i1; }
                    else         { v2 = u2; i2 = j2; }
                    v1 = u1; i1 = j1;
                } else if (u1 > v2) { v2 = u1; i2 = j1; }
            }
            if (r_ == 0) {
                const int row  = r0 + wr * 128 + m * 16 + g * 4 + reg;
                const size_t base = (size_t)row * 256 + (tcol * 2 + wc) * 2;
                pval[base] = v1; pval[base + 1] = v2;
                pidx[base] = i1; pidx[base + 1] = i2;
            }
        }
    }
}

// ---------- Kernel 3: exact fp32 re-check of candidates + gather ----------
__global__ __launch_bounds__(256) void finalize_kernel(
    const float* __restrict__ x, const float* __restrict__ lw,
    const float* __restrict__ lb, const float* __restrict__ embd,
    const float2* __restrict__ stats,
    const float* __restrict__ pval, const int* __restrict__ pidx,
    float* __restrict__ outq, float* __restrict__ outi)
{
    const int w    = threadIdx.x >> 6;
    const int lane = threadIdx.x & 63;
    const int row  = blockIdx.x * 4 + w;

    const float4 cv = *(const float4*)&pval[(size_t)row * 256 + lane * 4];
    const int4   ci = *(const int4*)  &pidx[(size_t)row * 256 + lane * 4];
    float vv[4] = { cv.x, cv.y, cv.z, cv.w };
    int   ii[4] = { ci.x, ci.y, ci.z, ci.w };

    float M = fmaxf(fmaxf(vv[0], vv[1]), fmaxf(vv[2], vv[3]));
    #pragma unroll
    for (int off = 1; off < 64; off <<= 1) M = fmaxf(M, __shfl_xor(M, off));
    const float T = M - MARGIN;

    const float2 st = stats[row];
    const float mu = st.x, rstd = st.y;
    const float* xr = x + (size_t)row * DIM + lane * 8;
    float4 x0 = *(const float4*)(xr);
    float4 x1 = *(const float4*)(xr + 4);
    float4 w0 = *(const float4*)(lw + lane * 8);
    float4 w1 = *(const float4*)(lw + lane * 8 + 4);
    float4 b0 = *(const float4*)(lb + lane * 8);
    float4 b1 = *(const float4*)(lb + lane * 8 + 4);
    float h[8] = {
        (x0.x - mu) * rstd * w0.x + b0.x, (x0.y - mu) * rstd * w0.y + b0.y,
        (x0.z - mu) * rstd * w0.z + b0.z, (x0.w - mu) * rstd * w0.w + b0.w,
        (x1.x - mu) * rstd * w1.x + b1.x, (x1.y - mu) * rstd * w1.y + b1.y,
        (x1.z - mu) * rstd * w1.z + b1.z, (x1.w - mu) * rstd * w1.w + b1.w };

    float bestv = -3.4e38f; int besti = 0x7fffffff;
    #pragma unroll
    for (int s = 0; s < 4; ++s) {
        unsigned long long msk = __ballot(vv[s] >= T);
        while (msk) {
            const int L = __ffsll(msk) - 1;
            msk &= msk - 1;
            const int cand = __shfl(ii[s], L);
            const float* er = embd + (size_t)cand * DIM + lane * 8;
            float4 e0 = *(const float4*)er;
            float4 e1 = *(const float4*)(er + 4);
            float d = h[0]*e0.x + h[1]*e0.y + h[2]*e0.z + h[3]*e0.w
                    + h[4]*e1.x + h[5]*e1.y + h[6]*e1.z + h[7]*e1.w;
            #pragma unroll
            for (int off = 1; off < 64; off <<= 1) d += __shfl_xor(d, off);
            if (d > bestv || (d == bestv && cand < besti)) { bestv = d; besti = cand; }
        }
    }

    const float* er = embd + (size_t)besti * DIM + lane * 8;
    float4 q0 = *(const float4*)er;
    float4 q1 = *(const float4*)(er + 4);
    float* qr = outq + (size_t)row * DIM + lane * 8;
    *(float4*)(qr)     = q0;
    *(float4*)(qr + 4) = q1;
    if (lane == 0) outi[row] = (float)besti;
}

extern "C" void kernel_launch(void* const* d_in, const int* in_sizes, int n_in,
                              void* d_out, int out_size, void* d_ws, size_t ws_size,
                              hipStream_t stream) {
    const float* x    = (const float*)d_in[0];
    const float* lnw  = (const float*)d_in[1];
    const float* lnb  = (const float*)d_in[2];
    const float* embd = (const float*)d_in[3];

    float* outq = (float*)d_out;
    float* outi = outq + (size_t)ROWS * DIM;

    char* ws = (char*)d_ws;
    float2*   stats = (float2*)ws;                                   // 64 KiB
    ushort_t* Hb    = (ushort_t*)(ws + (1 << 16));                   // 8 MiB
    ushort_t* Eb    = (ushort_t*)(ws + (1 << 16) + (8 << 20));       // 8 MiB
    float*    pval  = (float*)(ws + (1 << 16) + (16 << 20));         // 8 MiB
    int*      pidx  = (int*)  (ws + (1 << 16) + (24 << 20));         // 8 MiB

    prep_kernel<<<4096, 256, 0, stream>>>(x, lnw, lnb, embd, stats, Hb, Eb);

    gemm_argmax_kernel<<<2048, 256, 0, stream>>>(Hb, Eb, pval, pidx);

    finalize_kernel<<<ROWS / 4, 256, 0, stream>>>(x, lnw, lnb, embd, stats,
                                                  pval, pidx, outq, outi);
}

// Round 8
// 147.575 us; speedup vs baseline: 1.3276x; 1.1159x over previous
//
#include <hip/hip_runtime.h>
#include <hip/hip_bf16.h>

#define ROWS   8192
#define DIM    512
#define NCODES 8192
#define BM     256
#define BN     128
#define BK     64                     // i8 K-tile
#define NT     (DIM / BK)             // 8 K-tiles
#define MARGIN 3.0f

using i32x4 = __attribute__((ext_vector_type(4))) int;
typedef unsigned char u8;

__device__ __forceinline__ void gload_lds16(const void* g, void* l) {
    __builtin_amdgcn_global_load_lds((const __attribute__((address_space(1))) void*)g,
                                     (__attribute__((address_space(3))) void*)l,
                                     16, 0, 0);
}

__device__ __forceinline__ unsigned int pack4(int a, int b, int c, int d) {
    return (a & 255) | ((b & 255) << 8) | ((c & 255) << 16) | ((unsigned)(d & 255) << 24);
}

// ---------- Kernel 1: LN stats + i8-quantized h rows and embd rows ----------
// Per-row symmetric quantization: q = rint(v * 127/rowmax), scale = rowmax/127.
__global__ __launch_bounds__(256) void prep_kernel(
    const float* __restrict__ x, const float* __restrict__ lw,
    const float* __restrict__ lb, const float* __restrict__ embd,
    float2* __restrict__ stats, float* __restrict__ sh, float* __restrict__ se,
    u8* __restrict__ Hq, u8* __restrict__ Eq)
{
    const int w    = threadIdx.x >> 6;
    const int lane = threadIdx.x & 63;
    const int b    = blockIdx.x;

    if (b < 2048) {
        const int row = b * 4 + w;
        const float* xr = x + (size_t)row * DIM + lane * 8;
        float4 v0 = *(const float4*)(xr);
        float4 v1 = *(const float4*)(xr + 4);
        float s = (v0.x + v0.y) + (v0.z + v0.w) + (v1.x + v1.y) + (v1.z + v1.w);
        float q = v0.x*v0.x + v0.y*v0.y + v0.z*v0.z + v0.w*v0.w
                + v1.x*v1.x + v1.y*v1.y + v1.z*v1.z + v1.w*v1.w;
        #pragma unroll
        for (int off = 1; off < 64; off <<= 1) {
            s += __shfl_xor(s, off);
            q += __shfl_xor(q, off);
        }
        float mu   = s * (1.0f / DIM);
        float var  = q * (1.0f / DIM) - mu * mu;
        float rstd = rsqrtf(var + 1e-5f);
        if (lane == 0) stats[row] = make_float2(mu, rstd);

        float4 w0 = *(const float4*)(lw + lane * 8);
        float4 w1 = *(const float4*)(lw + lane * 8 + 4);
        float4 b0 = *(const float4*)(lb + lane * 8);
        float4 b1 = *(const float4*)(lb + lane * 8 + 4);
        float hv[8] = {
            (v0.x - mu) * rstd * w0.x + b0.x, (v0.y - mu) * rstd * w0.y + b0.y,
            (v0.z - mu) * rstd * w0.z + b0.z, (v0.w - mu) * rstd * w0.w + b0.w,
            (v1.x - mu) * rstd * w1.x + b1.x, (v1.y - mu) * rstd * w1.y + b1.y,
            (v1.z - mu) * rstd * w1.z + b1.z, (v1.w - mu) * rstd * w1.w + b1.w };

        float am = 0.0f;
        #pragma unroll
        for (int j = 0; j < 8; ++j) am = fmaxf(am, fabsf(hv[j]));
        #pragma unroll
        for (int off = 1; off < 64; off <<= 1) am = fmaxf(am, __shfl_xor(am, off));
        const float inv = (am > 0.0f) ? (127.0f / am) : 0.0f;
        if (lane == 0) sh[row] = am * (1.0f / 127.0f);

        int qi[8];
        #pragma unroll
        for (int j = 0; j < 8; ++j) qi[j] = __float2int_rn(hv[j] * inv);
        uint2 p = make_uint2(pack4(qi[0], qi[1], qi[2], qi[3]),
                             pack4(qi[4], qi[5], qi[6], qi[7]));
        *(uint2*)(Hq + (size_t)row * DIM + lane * 8) = p;
    } else {
        const int row = (b - 2048) * 4 + w;
        const float* er = embd + (size_t)row * DIM + lane * 8;
        float4 v0 = *(const float4*)(er);
        float4 v1 = *(const float4*)(er + 4);
        float ev[8] = { v0.x, v0.y, v0.z, v0.w, v1.x, v1.y, v1.z, v1.w };

        float am = 0.0f;
        #pragma unroll
        for (int j = 0; j < 8; ++j) am = fmaxf(am, fabsf(ev[j]));
        #pragma unroll
        for (int off = 1; off < 64; off <<= 1) am = fmaxf(am, __shfl_xor(am, off));
        const float inv = (am > 0.0f) ? (127.0f / am) : 0.0f;
        if (lane == 0) se[row] = am * (1.0f / 127.0f);

        int qi[8];
        #pragma unroll
        for (int j = 0; j < 8; ++j) qi[j] = __float2int_rn(ev[j] * inv);
        uint2 p = make_uint2(pack4(qi[0], qi[1], qi[2], qi[3]),
                             pack4(qi[4], qi[5], qi[6], qi[7]));
        *(uint2*)(Eq + (size_t)row * DIM + lane * 8) = p;
    }
}

// ---------- Kernel 2: 256x128 i8 MFMA GEMM, 2 blocks/CU, dbuf counted ----
// R7 skeleton ported to i8: BK=64 i8 rows are 64 B = byte-identical addressing
// (same T2 swizzle byte^=((row>>1)&3)<<4, same gload geometry, same vmcnt(6)),
// but NT 16->8, staging bytes halved, MFMA pipe-cycles halved (i8 2x rate).
__global__ __launch_bounds__(256, 2) void gemm_argmax_kernel(
    const u8* __restrict__ Hq, const u8* __restrict__ Eq,
    const float* __restrict__ sh, const float* __restrict__ se,
    float* __restrict__ pval, int* __restrict__ pidx)
{
    __shared__ __align__(16) u8 As[2][BM * BK];   // 2 x 16 KB
    __shared__ __align__(16) u8 Bs[2][BN * BK];   // 2 x 8 KB

    const int tid  = threadIdx.x;
    const int w    = tid >> 6;
    const int lane = tid & 63;
    const int r_   = lane & 15;
    const int g    = lane >> 4;
    const int wr   = w >> 1;          // row half (0,1) -> 128 rows
    const int wc   = w & 1;           // col half (0,1) -> 64 cols

    // T1: XCD map. xcd = bid&7 owns 4 row-panels x all 64 col-tiles, col-major.
    const int bid  = blockIdx.x;
    const int trow = ((bid & 7) << 2) | ((bid >> 3) & 3);   // 0..31
    const int tcol = bid >> 5;                              // 0..63
    const int r0 = trow * BM;
    const int n0 = tcol * BN;

    // staging: A 16 segs of 1KB (4/wave), B 8 segs (2/wave).
    // dest byte d = seg*1024 + lane*16 -> drow = seg*16+(lane>>2),
    // dcol=(lane&3)*16; inverse-swizzled SOURCE col byte = dcol ^ ((drow>>1)&3)<<4.
    const int da0 = (w * 4 + 0) * 16 + (lane >> 2);
    const int da1 = (w * 4 + 1) * 16 + (lane >> 2);
    const int da2 = (w * 4 + 2) * 16 + (lane >> 2);
    const int da3 = (w * 4 + 3) * 16 + (lane >> 2);
    const int db0 = (w * 2 + 0) * 16 + (lane >> 2);
    const int db1 = (w * 2 + 1) * 16 + (lane >> 2);
    const int lc  = (lane & 3) * 16;
    const u8* sA0 = Hq + (size_t)(r0 + da0) * DIM + (lc ^ (((da0 >> 1) & 3) << 4));
    const u8* sA1 = Hq + (size_t)(r0 + da1) * DIM + (lc ^ (((da1 >> 1) & 3) << 4));
    const u8* sA2 = Hq + (size_t)(r0 + da2) * DIM + (lc ^ (((da2 >> 1) & 3) << 4));
    const u8* sA3 = Hq + (size_t)(r0 + da3) * DIM + (lc ^ (((da3 >> 1) & 3) << 4));
    const u8* sB0 = Eq + (size_t)(n0 + db0) * DIM + (lc ^ (((db0 >> 1) & 3) << 4));
    const u8* sB1 = Eq + (size_t)(n0 + db1) * DIM + (lc ^ (((db1 >> 1) & 3) << 4));
    const int ua0 = (w * 4 + 0) * 1024, ua1 = (w * 4 + 1) * 1024;
    const int ua2 = (w * 4 + 2) * 1024, ua3 = (w * 4 + 3) * 1024;
    const int ub0 = (w * 2 + 0) * 1024, ub1 = (w * 2 + 1) * 1024;

    // swizzled ds_read bases (byte offsets within a slot); rows are 64 B.
    const int swz   = ((r_ >> 1) & 3) << 4;
    const int abase = (wr * 128 + r_) * 64 + ((g * 16) ^ swz);   // + m*1024
    const int bbase = (wc * 64  + r_) * 64 + ((g * 16) ^ swz);   // + n*1024

    i32x4 acc[8][4];
    #pragma unroll
    for (int m = 0; m < 8; ++m)
        #pragma unroll
        for (int n = 0; n < 4; ++n) acc[m][n] = (i32x4){0, 0, 0, 0};

#define STAGE(T) do {                                               \
        const int _ko = (T) * BK;                                   \
        const int _bf = (T) & 1;                                    \
        gload_lds16(sA0 + _ko, &As[_bf][ua0]);                      \
        gload_lds16(sA1 + _ko, &As[_bf][ua1]);                      \
        gload_lds16(sA2 + _ko, &As[_bf][ua2]);                      \
        gload_lds16(sA3 + _ko, &As[_bf][ua3]);                      \
        gload_lds16(sB0 + _ko, &Bs[_bf][ub0]);                      \
        gload_lds16(sB1 + _ko, &Bs[_bf][ub1]);                      \
    } while (0)
#define MF(M, N, AV, BV) \
        acc[M][N] = __builtin_amdgcn_mfma_i32_16x16x64_i8(AV, BV, acc[M][N], 0, 0, 0)

    STAGE(0);

    #pragma unroll
    for (int t = 0; t < NT; ++t) {
        if (t + 1 < NT) {
            STAGE(t + 1);
            asm volatile("s_waitcnt vmcnt(6)" ::: "memory");  // tile t landed
        } else {
            asm volatile("s_waitcnt vmcnt(0)" ::: "memory");
        }
        __builtin_amdgcn_s_barrier();

        const char* Ab = (const char*)&As[t & 1][0];
        const char* Bb = (const char*)&Bs[t & 1][0];
        i32x4 a0 = *(const i32x4*)(Ab + abase + 0 * 1024);
        i32x4 a1 = *(const i32x4*)(Ab + abase + 1 * 1024);
        i32x4 a2 = *(const i32x4*)(Ab + abase + 2 * 1024);
        i32x4 a3 = *(const i32x4*)(Ab + abase + 3 * 1024);
        i32x4 a4 = *(const i32x4*)(Ab + abase + 4 * 1024);
        i32x4 a5 = *(const i32x4*)(Ab + abase + 5 * 1024);
        i32x4 a6 = *(const i32x4*)(Ab + abase + 6 * 1024);
        i32x4 a7 = *(const i32x4*)(Ab + abase + 7 * 1024);
        i32x4 b0 = *(const i32x4*)(Bb + bbase + 0 * 1024);
        i32x4 b1 = *(const i32x4*)(Bb + bbase + 1 * 1024);
        i32x4 b2 = *(const i32x4*)(Bb + bbase + 2 * 1024);
        i32x4 b3 = *(const i32x4*)(Bb + bbase + 3 * 1024);

        __builtin_amdgcn_s_setprio(1);
        MF(0, 0, a0, b0); MF(0, 1, a0, b1); MF(0, 2, a0, b2); MF(0, 3, a0, b3);
        MF(1, 0, a1, b0); MF(1, 1, a1, b1); MF(1, 2, a1, b2); MF(1, 3, a1, b3);
        MF(2, 0, a2, b0); MF(2, 1, a2, b1); MF(2, 2, a2, b2); MF(2, 3, a2, b3);
        MF(3, 0, a3, b0); MF(3, 1, a3, b1); MF(3, 2, a3, b2); MF(3, 3, a3, b3);
        MF(4, 0, a4, b0); MF(4, 1, a4, b1); MF(4, 2, a4, b2); MF(4, 3, a4, b3);
        MF(5, 0, a5, b0); MF(5, 1, a5, b1); MF(5, 2, a5, b2); MF(5, 3, a5, b3);
        MF(6, 0, a6, b0); MF(6, 1, a6, b1); MF(6, 2, a6, b2); MF(6, 3, a6, b3);
        MF(7, 0, a7, b0); MF(7, 1, a7, b1); MF(7, 2, a7, b2); MF(7, 3, a7, b3);
        __builtin_amdgcn_s_setprio(0);

        __builtin_amdgcn_s_barrier();   // closing: slot (t&1) readers done
    }

#undef MF
#undef STAGE

    // ---- epilogue: scale to approx logits, per-row top-2 over 64-col chunk ----
    const int cb = n0 + wc * 64;
    float sev[4];
    #pragma unroll
    for (int n = 0; n < 4; ++n) sev[n] = se[cb + n * 16 + r_];

    #pragma unroll
    for (int m = 0; m < 8; ++m) {
        const float4 sc4 = *(const float4*)&sh[r0 + wr * 128 + m * 16 + g * 4];
        #pragma unroll
        for (int reg = 0; reg < 4; ++reg) {
            const float sc = (reg == 0) ? sc4.x : (reg == 1) ? sc4.y
                             : (reg == 2) ? sc4.z : sc4.w;
            float v1 = (float)acc[m][0][reg] * (sc * sev[0]); int i1 = cb + r_;
            float v2 = -3.4e38f;                              int i2 = 0;
            #pragma unroll
            for (int n = 1; n < 4; ++n) {
                float vv = (float)acc[m][n][reg] * (sc * sev[n]);
                int   cc = cb + n * 16 + r_;
                if (vv > v1)      { v2 = v1; i2 = i1; v1 = vv; i1 = cc; }
                else if (vv > v2) { v2 = vv; i2 = cc; }
            }
            #pragma unroll
            for (int off = 1; off < 16; off <<= 1) {
                float u1 = __shfl_xor(v1, off);
                int   j1 = __shfl_xor(i1, off);
                float u2 = __shfl_xor(v2, off);
                int   j2 = __shfl_xor(i2, off);
                if (u1 > v1) {
                    if (v1 > u2) { v2 = v1; i2 = i1; }
                    else         { v2 = u2; i2 = j2; }
                    v1 = u1; i1 = j1;
                } else if (u1 > v2) { v2 = u1; i2 = j1; }
            }
            if (r_ == 0) {
                const int row  = r0 + wr * 128 + m * 16 + g * 4 + reg;
                const size_t base = (size_t)row * 256 + (tcol * 2 + wc) * 2;
                pval[base] = v1; pval[base + 1] = v2;
                pidx[base] = i1; pidx[base + 1] = i2;
            }
        }
    }
}

// ---------- Kernel 3: exact fp32 re-check of candidates + gather ----------
__global__ __launch_bounds__(256) void finalize_kernel(
    const float* __restrict__ x, const float* __restrict__ lw,
    const float* __restrict__ lb, const float* __restrict__ embd,
    const float2* __restrict__ stats,
    const float* __restrict__ pval, const int* __restrict__ pidx,
    float* __restrict__ outq, float* __restrict__ outi)
{
    const int w    = threadIdx.x >> 6;
    const int lane = threadIdx.x & 63;
    const int row  = blockIdx.x * 4 + w;

    const float4 cv = *(const float4*)&pval[(size_t)row * 256 + lane * 4];
    const int4   ci = *(const int4*)  &pidx[(size_t)row * 256 + lane * 4];
    float vv[4] = { cv.x, cv.y, cv.z, cv.w };
    int   ii[4] = { ci.x, ci.y, ci.z, ci.w };

    float M = fmaxf(fmaxf(vv[0], vv[1]), fmaxf(vv[2], vv[3]));
    #pragma unroll
    for (int off = 1; off < 64; off <<= 1) M = fmaxf(M, __shfl_xor(M, off));
    const float T = M - MARGIN;

    const float2 st = stats[row];
    const float mu = st.x, rstd = st.y;
    const float* xr = x + (size_t)row * DIM + lane * 8;
    float4 x0 = *(const float4*)(xr);
    float4 x1 = *(const float4*)(xr + 4);
    float4 w0 = *(const float4*)(lw + lane * 8);
    float4 w1 = *(const float4*)(lw + lane * 8 + 4);
    float4 b0 = *(const float4*)(lb + lane * 8);
    float4 b1 = *(const float4*)(lb + lane * 8 + 4);
    float h[8] = {
        (x0.x - mu) * rstd * w0.x + b0.x, (x0.y - mu) * rstd * w0.y + b0.y,
        (x0.z - mu) * rstd * w0.z + b0.z, (x0.w - mu) * rstd * w0.w + b0.w,
        (x1.x - mu) * rstd * w1.x + b1.x, (x1.y - mu) * rstd * w1.y + b1.y,
        (x1.z - mu) * rstd * w1.z + b1.z, (x1.w - mu) * rstd * w1.w + b1.w };

    float bestv = -3.4e38f; int besti = 0x7fffffff;
    #pragma unroll
    for (int s = 0; s < 4; ++s) {
        unsigned long long msk = __ballot(vv[s] >= T);
        while (msk) {
            const int L = __ffsll(msk) - 1;
            msk &= msk - 1;
            const int cand = __shfl(ii[s], L);
            const float* er = embd + (size_t)cand * DIM + lane * 8;
            float4 e0 = *(const float4*)er;
            float4 e1 = *(const float4*)(er + 4);
            float d = h[0]*e0.x + h[1]*e0.y + h[2]*e0.z + h[3]*e0.w
                    + h[4]*e1.x + h[5]*e1.y + h[6]*e1.z + h[7]*e1.w;
            #pragma unroll
            for (int off = 1; off < 64; off <<= 1) d += __shfl_xor(d, off);
            if (d > bestv || (d == bestv && cand < besti)) { bestv = d; besti = cand; }
        }
    }

    const float* er = embd + (size_t)besti * DIM + lane * 8;
    float4 q0 = *(const float4*)er;
    float4 q1 = *(const float4*)(er + 4);
    float* qr = outq + (size_t)row * DIM + lane * 8;
    *(float4*)(qr)     = q0;
    *(float4*)(qr + 4) = q1;
    if (lane == 0) outi[row] = (float)besti;
}

extern "C" void kernel_launch(void* const* d_in, const int* in_sizes, int n_in,
                              void* d_out, int out_size, void* d_ws, size_t ws_size,
                              hipStream_t stream) {
    const float* x    = (const float*)d_in[0];
    const float* lnw  = (const float*)d_in[1];
    const float* lnb  = (const float*)d_in[2];
    const float* embd = (const float*)d_in[3];

    float* outq = (float*)d_out;
    float* outi = outq + (size_t)ROWS * DIM;

    char* ws = (char*)d_ws;
    float2* stats = (float2*)ws;                                  // 64 KiB
    float*  sh    = (float*)(ws + (1 << 16));                     // 32 KiB
    float*  se    = (float*)(ws + (1 << 16) + (1 << 15));         // 32 KiB
    u8*     Hq    = (u8*)(ws + (1 << 17));                        // 4 MiB
    u8*     Eq    = (u8*)(ws + (1 << 17) + (4 << 20));            // 4 MiB
    float*  pval  = (float*)(ws + (1 << 17) + (8 << 20));         // 8 MiB
    int*    pidx  = (int*)  (ws + (1 << 17) + (16 << 20));        // 8 MiB

    prep_kernel<<<4096, 256, 0, stream>>>(x, lnw, lnb, embd, stats, sh, se, Hq, Eq);

    gemm_argmax_kernel<<<2048, 256, 0, stream>>>(Hq, Eq, sh, se, pval, pidx);

    finalize_kernel<<<ROWS / 4, 256, 0, stream>>>(x, lnw, lnb, embd, stats,
                                                  pval, pidx, outq, outi);
}

// Round 10
// 107.829 us; speedup vs baseline: 1.8170x; 1.3686x over previous
//
#include <hip/hip_runtime.h>
#include <hip/hip_bf16.h>

#define ROWS   8192
#define DIM    512
#define NCODES 8192
#define BM     256
#define BN     128
#define BK     64                     // i8 K-tile
#define NT     (DIM / BK)             // 8 K-tiles
#define MARGIN 3.0f

using i32x4 = __attribute__((ext_vector_type(4))) int;
typedef unsigned char u8;

__device__ __forceinline__ void gload_lds16(const void* g, void* l) {
    __builtin_amdgcn_global_load_lds((const __attribute__((address_space(1))) void*)g,
                                     (__attribute__((address_space(3))) void*)l,
                                     16, 0, 0);
}

__device__ __forceinline__ unsigned int pack4(int a, int b, int c, int d) {
    return (a & 255) | ((b & 255) << 8) | ((c & 255) << 16) | ((unsigned)(d & 255) << 24);
}

// ---------- Kernel 1: LN+quant(H, per-row) | quant(E, per-64-row-chunk) ----------
__global__ __launch_bounds__(256) void prep_kernel(
    const float* __restrict__ x, const float* __restrict__ lw,
    const float* __restrict__ lb, const float* __restrict__ embd,
    float2* __restrict__ stats, float* __restrict__ sh, float* __restrict__ se,
    u8* __restrict__ Hq, u8* __restrict__ Eq)
{
    __shared__ float red[4];
    const int w    = threadIdx.x >> 6;
    const int lane = threadIdx.x & 63;
    const int b    = blockIdx.x;

    if (b < 2048) {                       // ---- H rows (per-row scale) ----
        const int row = b * 4 + w;
        const float* xr = x + (size_t)row * DIM + lane * 8;
        float4 v0 = *(const float4*)(xr);
        float4 v1 = *(const float4*)(xr + 4);
        float s = (v0.x + v0.y) + (v0.z + v0.w) + (v1.x + v1.y) + (v1.z + v1.w);
        float q = v0.x*v0.x + v0.y*v0.y + v0.z*v0.z + v0.w*v0.w
                + v1.x*v1.x + v1.y*v1.y + v1.z*v1.z + v1.w*v1.w;
        #pragma unroll
        for (int off = 1; off < 64; off <<= 1) {
            s += __shfl_xor(s, off);
            q += __shfl_xor(q, off);
        }
        float mu   = s * (1.0f / DIM);
        float var  = q * (1.0f / DIM) - mu * mu;
        float rstd = rsqrtf(var + 1e-5f);
        if (lane == 0) stats[row] = make_float2(mu, rstd);

        float4 w0 = *(const float4*)(lw + lane * 8);
        float4 w1 = *(const float4*)(lw + lane * 8 + 4);
        float4 b0 = *(const float4*)(lb + lane * 8);
        float4 b1 = *(const float4*)(lb + lane * 8 + 4);
        float hv[8] = {
            (v0.x - mu) * rstd * w0.x + b0.x, (v0.y - mu) * rstd * w0.y + b0.y,
            (v0.z - mu) * rstd * w0.z + b0.z, (v0.w - mu) * rstd * w0.w + b0.w,
            (v1.x - mu) * rstd * w1.x + b1.x, (v1.y - mu) * rstd * w1.y + b1.y,
            (v1.z - mu) * rstd * w1.z + b1.z, (v1.w - mu) * rstd * w1.w + b1.w };

        float am = 0.0f;
        #pragma unroll
        for (int j = 0; j < 8; ++j) am = fmaxf(am, fabsf(hv[j]));
        #pragma unroll
        for (int off = 1; off < 64; off <<= 1) am = fmaxf(am, __shfl_xor(am, off));
        const float inv = (am > 0.0f) ? (127.0f / am) : 0.0f;
        if (lane == 0) sh[row] = am * (1.0f / 127.0f);

        int qi[8];
        #pragma unroll
        for (int j = 0; j < 8; ++j) qi[j] = __float2int_rn(hv[j] * inv);
        uint2 p = make_uint2(pack4(qi[0], qi[1], qi[2], qi[3]),
                             pack4(qi[4], qi[5], qi[6], qi[7]));
        *(uint2*)(Hq + (size_t)row * DIM + lane * 8) = p;
    } else {                              // ---- E 64-row chunks (per-chunk scale) ----
        const int chunk = b - 2048;                    // 0..127
        const int row   = chunk * 64 + (threadIdx.x >> 2);
        const int off0  = (threadIdx.x & 3) * 128;
        const float* er = embd + (size_t)row * DIM + off0;

        float4 v[32];
        float am = 0.0f;
        #pragma unroll
        for (int j = 0; j < 32; ++j) {
            v[j] = *(const float4*)(er + j * 4);
            am = fmaxf(am, fmaxf(fmaxf(fabsf(v[j].x), fabsf(v[j].y)),
                                 fmaxf(fabsf(v[j].z), fabsf(v[j].w))));
        }
        #pragma unroll
        for (int off = 1; off < 64; off <<= 1) am = fmaxf(am, __shfl_xor(am, off));
        if (lane == 0) red[w] = am;
        __syncthreads();
        am = fmaxf(fmaxf(red[0], red[1]), fmaxf(red[2], red[3]));

        const float inv = (am > 0.0f) ? (127.0f / am) : 0.0f;
        if (threadIdx.x == 0) se[chunk] = am * (1.0f / 127.0f);

        u8* out = Eq + (size_t)row * DIM + off0;
        #pragma unroll
        for (int j = 0; j < 32; j += 4) {
            uint4 o;
            o.x = pack4(__float2int_rn(v[j+0].x*inv), __float2int_rn(v[j+0].y*inv),
                        __float2int_rn(v[j+0].z*inv), __float2int_rn(v[j+0].w*inv));
            o.y = pack4(__float2int_rn(v[j+1].x*inv), __float2int_rn(v[j+1].y*inv),
                        __float2int_rn(v[j+1].z*inv), __float2int_rn(v[j+1].w*inv));
            o.z = pack4(__float2int_rn(v[j+2].x*inv), __float2int_rn(v[j+2].y*inv),
                        __float2int_rn(v[j+2].z*inv), __float2int_rn(v[j+2].w*inv));
            o.w = pack4(__float2int_rn(v[j+3].x*inv), __float2int_rn(v[j+3].y*inv),
                        __float2int_rn(v[j+3].z*inv), __float2int_rn(v[j+3].w*inv));
            *(uint4*)(out + j * 4) = o;
        }
    }
}

// ---------- Kernel 2: 256x128 i8 MFMA GEMM, 3-slot ring 2-deep, i32 argmax ----
// FIX vs R9: K_TILE slot arg for tiles 3..5 is tile%3 (0,1,2), NOT the tile
// number (3,4,5 indexed past the 3-slot ring into Bs/garbage).
__global__ __launch_bounds__(256, 2) void gemm_argmax_kernel(
    const u8* __restrict__ Hq, const u8* __restrict__ Eq,
    const float* __restrict__ sh, const float* __restrict__ se,
    float* __restrict__ pval, int* __restrict__ pidx)
{
    __shared__ __align__(16) u8 As[3][BM * BK];   // 3 x 16 KB
    __shared__ __align__(16) u8 Bs[3][BN * BK];   // 3 x 8 KB

    const int tid  = threadIdx.x;
    const int w    = tid >> 6;
    const int lane = tid & 63;
    const int r_   = lane & 15;
    const int g    = lane >> 4;
    const int wr   = w >> 1;          // row half (0,1) -> 128 rows
    const int wc   = w & 1;           // col half (0,1) -> 64 cols

    // T1: XCD map. xcd = bid&7 owns 4 row-panels x all 64 col-tiles, col-major.
    const int bid  = blockIdx.x;
    const int trow = ((bid & 7) << 2) | ((bid >> 3) & 3);   // 0..31
    const int tcol = bid >> 5;                              // 0..63
    const int r0 = trow * BM;
    const int n0 = tcol * BN;

    // staging geometry (T2 swizzle byte^=((row>>1)&3)<<4, pre-swizzled source)
    const int da0 = (w * 4 + 0) * 16 + (lane >> 2);
    const int da1 = (w * 4 + 1) * 16 + (lane >> 2);
    const int da2 = (w * 4 + 2) * 16 + (lane >> 2);
    const int da3 = (w * 4 + 3) * 16 + (lane >> 2);
    const int db0 = (w * 2 + 0) * 16 + (lane >> 2);
    const int db1 = (w * 2 + 1) * 16 + (lane >> 2);
    const int lc  = (lane & 3) * 16;
    const u8* sA0 = Hq + (size_t)(r0 + da0) * DIM + (lc ^ (((da0 >> 1) & 3) << 4));
    const u8* sA1 = Hq + (size_t)(r0 + da1) * DIM + (lc ^ (((da1 >> 1) & 3) << 4));
    const u8* sA2 = Hq + (size_t)(r0 + da2) * DIM + (lc ^ (((da2 >> 1) & 3) << 4));
    const u8* sA3 = Hq + (size_t)(r0 + da3) * DIM + (lc ^ (((da3 >> 1) & 3) << 4));
    const u8* sB0 = Eq + (size_t)(n0 + db0) * DIM + (lc ^ (((db0 >> 1) & 3) << 4));
    const u8* sB1 = Eq + (size_t)(n0 + db1) * DIM + (lc ^ (((db1 >> 1) & 3) << 4));
    const int ua0 = (w * 4 + 0) * 1024, ua1 = (w * 4 + 1) * 1024;
    const int ua2 = (w * 4 + 2) * 1024, ua3 = (w * 4 + 3) * 1024;
    const int ub0 = (w * 2 + 0) * 1024, ub1 = (w * 2 + 1) * 1024;

    // swizzled ds_read bases (byte offsets within a slot); rows are 64 B.
    const int swz   = ((r_ >> 1) & 3) << 4;
    const int abase = (wr * 128 + r_) * 64 + ((g * 16) ^ swz);   // + m*1024
    const int bbase = (wc * 64  + r_) * 64 + ((g * 16) ^ swz);   // + n*1024

    i32x4 acc[8][4];
    #pragma unroll
    for (int m = 0; m < 8; ++m)
        #pragma unroll
        for (int n = 0; n < 4; ++n) acc[m][n] = (i32x4){0, 0, 0, 0};

#define STAGE(T, SL) do {                                           \
        const int _ko = (T) * BK;                                   \
        gload_lds16(sA0 + _ko, &As[SL][ua0]);                       \
        gload_lds16(sA1 + _ko, &As[SL][ua1]);                       \
        gload_lds16(sA2 + _ko, &As[SL][ua2]);                       \
        gload_lds16(sA3 + _ko, &As[SL][ua3]);                       \
        gload_lds16(sB0 + _ko, &Bs[SL][ub0]);                       \
        gload_lds16(sB1 + _ko, &Bs[SL][ub1]);                       \
    } while (0)
#define MF(M, N, AV, BV) \
        acc[M][N] = __builtin_amdgcn_mfma_i32_16x16x64_i8(AV, BV, acc[M][N], 0, 0, 0)

#define K_TILE(SL, STG, VMSTR) do {                                 \
        STG;                                                        \
        asm volatile("s_waitcnt vmcnt(" VMSTR ")" ::: "memory");    \
        __builtin_amdgcn_s_barrier();                               \
        const char* Ab = (const char*)&As[SL][0];                   \
        const char* Bb = (const char*)&Bs[SL][0];                   \
        i32x4 a0 = *(const i32x4*)(Ab + abase + 0 * 1024);          \
        i32x4 a1 = *(const i32x4*)(Ab + abase + 1 * 1024);          \
        i32x4 a2 = *(const i32x4*)(Ab + abase + 2 * 1024);          \
        i32x4 a3 = *(const i32x4*)(Ab + abase + 3 * 1024);          \
        i32x4 a4 = *(const i32x4*)(Ab + abase + 4 * 1024);          \
        i32x4 a5 = *(const i32x4*)(Ab + abase + 5 * 1024);          \
        i32x4 a6 = *(const i32x4*)(Ab + abase + 6 * 1024);          \
        i32x4 a7 = *(const i32x4*)(Ab + abase + 7 * 1024);          \
        i32x4 b0 = *(const i32x4*)(Bb + bbase + 0 * 1024);          \
        i32x4 b1 = *(const i32x4*)(Bb + bbase + 1 * 1024);          \
        i32x4 b2 = *(const i32x4*)(Bb + bbase + 2 * 1024);          \
        i32x4 b3 = *(const i32x4*)(Bb + bbase + 3 * 1024);          \
        __builtin_amdgcn_s_setprio(1);                              \
        MF(0, 0, a0, b0); MF(0, 1, a0, b1); MF(0, 2, a0, b2); MF(0, 3, a0, b3); \
        MF(1, 0, a1, b0); MF(1, 1, a1, b1); MF(1, 2, a1, b2); MF(1, 3, a1, b3); \
        MF(2, 0, a2, b0); MF(2, 1, a2, b1); MF(2, 2, a2, b2); MF(2, 3, a2, b3); \
        MF(3, 0, a3, b0); MF(3, 1, a3, b1); MF(3, 2, a3, b2); MF(3, 3, a3, b3); \
        MF(4, 0, a4, b0); MF(4, 1, a4, b1); MF(4, 2, a4, b2); MF(4, 3, a4, b3); \
        MF(5, 0, a5, b0); MF(5, 1, a5, b1); MF(5, 2, a5, b2); MF(5, 3, a5, b3); \
        MF(6, 0, a6, b0); MF(6, 1, a6, b1); MF(6, 2, a6, b2); MF(6, 3, a6, b3); \
        MF(7, 0, a7, b0); MF(7, 1, a7, b1); MF(7, 2, a7, b2); MF(7, 3, a7, b3); \
        __builtin_amdgcn_s_setprio(0);                              \
        __builtin_amdgcn_s_barrier();                               \
    } while (0)

    // prologue: tiles 0,1 staged; loop keeps 2 tiles in flight (vmcnt 12)
    STAGE(0, 0);
    STAGE(1, 1);

    K_TILE(0, STAGE(2, 2), "12");   // tile 0, slot 0
    K_TILE(1, STAGE(3, 0), "12");   // tile 1, slot 1
    K_TILE(2, STAGE(4, 1), "12");   // tile 2, slot 2
    K_TILE(0, STAGE(5, 2), "12");   // tile 3, slot 0
    K_TILE(1, STAGE(6, 0), "12");   // tile 4, slot 1
    K_TILE(2, STAGE(7, 1), "12");   // tile 5, slot 2
    K_TILE(0, , "6");               // tile 6, slot 0
    K_TILE(1, , "0");               // tile 7, slot 1

#undef K_TILE
#undef MF
#undef STAGE

    // ---- epilogue: pure-i32 packed-key top-2 per (row, 64-col chunk) ----
    const int cb    = n0 + wc * 64;
    const float se_ch = se[tcol * 2 + wc];
    #pragma unroll
    for (int m = 0; m < 8; ++m) {
        const float4 sc4 = *(const float4*)&sh[r0 + wr * 128 + m * 16 + g * 4];
        #pragma unroll
        for (int reg = 0; reg < 4; ++reg) {
            int ka = (acc[m][0][reg] << 7) | (63 - r_);
            int kb = (acc[m][1][reg] << 7) | (47 - r_);
            int kc = (acc[m][2][reg] << 7) | (31 - r_);
            int kd = (acc[m][3][reg] << 7) | (15 - r_);
            int m1 = max(ka, kb), n1 = min(ka, kb);
            int m2 = max(kc, kd), n2 = min(kc, kd);
            int k1 = max(m1, m2);
            int k2 = max(min(m1, m2), max(n1, n2));
            #pragma unroll
            for (int off = 1; off < 16; off <<= 1) {
                int b1 = __shfl_xor(k1, off);
                int b2 = __shfl_xor(k2, off);
                k2 = max(max(k2, b2), min(k1, b1));
                k1 = max(k1, b1);
            }
            if (r_ == 0) {
                const float sc = (reg == 0) ? sc4.x : (reg == 1) ? sc4.y
                                 : (reg == 2) ? sc4.z : sc4.w;
                const int row = r0 + wr * 128 + m * 16 + g * 4 + reg;
                const size_t base = (size_t)row * 256 + (tcol * 2 + wc) * 2;
                pval[base]     = (float)(k1 >> 7) * (sc * se_ch);
                pval[base + 1] = (float)(k2 >> 7) * (sc * se_ch);
                pidx[base]     = cb + 63 - (k1 & 63);
                pidx[base + 1] = cb + 63 - (k2 & 63);
            }
        }
    }
}

// ---------- Kernel 3: exact fp32 re-check of candidates + gather ----------
__global__ __launch_bounds__(256) void finalize_kernel(
    const float* __restrict__ x, const float* __restrict__ lw,
    const float* __restrict__ lb, const float* __restrict__ embd,
    const float2* __restrict__ stats,
    const float* __restrict__ pval, const int* __restrict__ pidx,
    float* __restrict__ outq, float* __restrict__ outi)
{
    const int w    = threadIdx.x >> 6;
    const int lane = threadIdx.x & 63;
    const int row  = blockIdx.x * 4 + w;

    const float4 cv = *(const float4*)&pval[(size_t)row * 256 + lane * 4];
    const int4   ci = *(const int4*)  &pidx[(size_t)row * 256 + lane * 4];
    float vv[4] = { cv.x, cv.y, cv.z, cv.w };
    int   ii[4] = { ci.x, ci.y, ci.z, ci.w };

    float M = fmaxf(fmaxf(vv[0], vv[1]), fmaxf(vv[2], vv[3]));
    #pragma unroll
    for (int off = 1; off < 64; off <<= 1) M = fmaxf(M, __shfl_xor(M, off));
    const float T = M - MARGIN;

    const float2 st = stats[row];
    const float mu = st.x, rstd = st.y;
    const float* xr = x + (size_t)row * DIM + lane * 8;
    float4 x0 = *(const float4*)(xr);
    float4 x1 = *(const float4*)(xr + 4);
    float4 w0 = *(const float4*)(lw + lane * 8);
    float4 w1 = *(const float4*)(lw + lane * 8 + 4);
    float4 b0 = *(const float4*)(lb + lane * 8);
    float4 b1 = *(const float4*)(lb + lane * 8 + 4);
    float h[8] = {
        (x0.x - mu) * rstd * w0.x + b0.x, (x0.y - mu) * rstd * w0.y + b0.y,
        (x0.z - mu) * rstd * w0.z + b0.z, (x0.w - mu) * rstd * w0.w + b0.w,
        (x1.x - mu) * rstd * w1.x + b1.x, (x1.y - mu) * rstd * w1.y + b1.y,
        (x1.z - mu) * rstd * w1.z + b1.z, (x1.w - mu) * rstd * w1.w + b1.w };

    float bestv = -3.4e38f; int besti = 0x7fffffff;
    #pragma unroll
    for (int s = 0; s < 4; ++s) {
        unsigned long long msk = __ballot(vv[s] >= T);
        while (msk) {
            const int L = __ffsll(msk) - 1;
            msk &= msk - 1;
            const int cand = __shfl(ii[s], L);
            const float* er = embd + (size_t)cand * DIM + lane * 8;
            float4 e0 = *(const float4*)er;
            float4 e1 = *(const float4*)(er + 4);
            float d = h[0]*e0.x + h[1]*e0.y + h[2]*e0.z + h[3]*e0.w
                    + h[4]*e1.x + h[5]*e1.y + h[6]*e1.z + h[7]*e1.w;
            #pragma unroll
            for (int off = 1; off < 64; off <<= 1) d += __shfl_xor(d, off);
            if (d > bestv || (d == bestv && cand < besti)) { bestv = d; besti = cand; }
        }
    }

    const float* er = embd + (size_t)besti * DIM + lane * 8;
    float4 q0 = *(const float4*)er;
    float4 q1 = *(const float4*)(er + 4);
    float* qr = outq + (size_t)row * DIM + lane * 8;
    *(float4*)(qr)     = q0;
    *(float4*)(qr + 4) = q1;
    if (lane == 0) outi[row] = (float)besti;
}

extern "C" void kernel_launch(void* const* d_in, const int* in_sizes, int n_in,
                              void* d_out, int out_size, void* d_ws, size_t ws_size,
                              hipStream_t stream) {
    const float* x    = (const float*)d_in[0];
    const float* lnw  = (const float*)d_in[1];
    const float* lnb  = (const float*)d_in[2];
    const float* embd = (const float*)d_in[3];

    float* outq = (float*)d_out;
    float* outi = outq + (size_t)ROWS * DIM;

    char* ws = (char*)d_ws;
    float2* stats = (float2*)ws;                                  // 64 KiB
    float*  sh    = (float*)(ws + (1 << 16));                     // 32 KiB
    float*  se    = (float*)(ws + (1 << 16) + (1 << 15));         // 512 B used
    u8*     Hq    = (u8*)(ws + (1 << 17));                        // 4 MiB
    u8*     Eq    = (u8*)(ws + (1 << 17) + (4 << 20));            // 4 MiB
    float*  pval  = (float*)(ws + (1 << 17) + (8 << 20));         // 8 MiB
    int*    pidx  = (int*)  (ws + (1 << 17) + (16 << 20));        // 8 MiB

    prep_kernel<<<2176, 256, 0, stream>>>(x, lnw, lnb, embd, stats, sh, se, Hq, Eq);

    gemm_argmax_kernel<<<2048, 256, 0, stream>>>(Hq, Eq, sh, se, pval, pidx);

    finalize_kernel<<<ROWS / 4, 256, 0, stream>>>(x, lnw, lnb, embd, stats,
                                                  pval, pidx, outq, outi);
}